// Round 1
// baseline (95.044 us; speedup 1.0000x reference)
//
#include <hip/hip_runtime.h>
#include <hip/hip_bf16.h>

typedef int v4i __attribute__((ext_vector_type(4)));

// Padded quantized activations: qp[n][hp][wp][c], hp,wp in [0,114), c in [0,64)
#define QP_N 32
#define QP_HP 114
#define QP_WP 114
#define QP_C 64
#define QP_BYTES ((size_t)QP_N * QP_HP * QP_WP * QP_C)   // 26,615,808

// ---------------------------------------------------------------------------
// Kernel 1: quantize + NCHW -> padded NHWC int8 transpose.
// One block per (n, h). LDS tile 64c x 112w fp32.
// ---------------------------------------------------------------------------
__global__ __launch_bounds__(256) void quantize_kernel(const float* __restrict__ x,
                                                       signed char* __restrict__ qp) {
    int nb = blockIdx.x;            // 0..3583
    int n = nb / 112;
    int h = nb - n * 112;
    __shared__ float lds[64][112];
    int t = threadIdx.x;

    const float* xp = x + (size_t)n * 64 * 12544 + h * 112;  // x[n][c][h][w], c-plane stride 12544
#pragma unroll
    for (int j = 0; j < 7; ++j) {
        int fidx = j * 256 + t;      // 1792 float4 chunks total (64 rows * 28)
        int c = fidx / 28;
        int f = fidx - c * 28;
        float4 v = *reinterpret_cast<const float4*>(xp + (size_t)c * 12544 + f * 4);
        *reinterpret_cast<float4*>(&lds[c][f * 4]) = v;
    }
    __syncthreads();

    if (t < 224) {
        int w = t >> 1;              // 0..111
        int ch = (t & 1) * 32;       // channel half: 0 or 32
        int dw[8];
#pragma unroll
        for (int q = 0; q < 8; ++q) {
            int d = 0;
#pragma unroll
            for (int b = 0; b < 4; ++b) {
                float v = lds[ch + q * 4 + b][w];
                float s = rintf(v * 20.0f);                 // round-half-to-even, matches jnp.round
                s = fminf(127.0f, fmaxf(-128.0f, s));
                int iv = (int)s;
                d |= (iv & 0xff) << (8 * b);
            }
            dw[q] = d;
        }
        size_t qoff = ((size_t)(n * QP_HP + (h + 1)) * QP_WP + (w + 1)) * QP_C + ch;
        int4* dst = reinterpret_cast<int4*>(qp + qoff);
        dst[0] = make_int4(dw[0], dw[1], dw[2], dw[3]);
        dst[1] = make_int4(dw[4], dw[5], dw[6], dw[7]);
    }
}

// ---------------------------------------------------------------------------
// Kernel 2: weight prepack into MFMA A-fragment layout.
// wb[frag][lane][16B], frag = (kh*3+kw)*4 + g.
// A-frag (M=co x K=ci): lane l holds A[m = l&15][k = (l>>4)*16 + j], j=0..15.
// co = g*16 + (l&15), ci = (l>>4)*16 + j.
// quant_weight arrives widened to int32: qw[((co*64+ci)*3+kh)*3+kw]
// ---------------------------------------------------------------------------
__global__ __launch_bounds__(256) void prepack_kernel(const int* __restrict__ qw,
                                                      signed char* __restrict__ wb) {
    int t = blockIdx.x * 256 + threadIdx.x;
    if (t >= 36 * 64) return;
    int lane = t & 63;
    int frag = t >> 6;               // 0..35
    int g = frag & 3;
    int tap = frag >> 2;             // kh*3+kw
    int kh = tap / 3;
    int kw = tap - kh * 3;
    int co = g * 16 + (lane & 15);
    int cibase = (lane >> 4) * 16;
    int dwv[4];
#pragma unroll
    for (int d = 0; d < 4; ++d) {
        int acc = 0;
#pragma unroll
        for (int b = 0; b < 4; ++b) {
            int ci = cibase + d * 4 + b;
            int v = qw[((co * 64 + ci) * 3 + kh) * 3 + kw];
            acc |= (v & 0xff) << (8 * b);
        }
        dwv[d] = acc;
    }
    *reinterpret_cast<int4*>(wb + (size_t)t * 16) = make_int4(dwv[0], dwv[1], dwv[2], dwv[3]);
}

// ---------------------------------------------------------------------------
// Kernel 3: implicit-GEMM conv. One wave per 16-pixel block (16 consecutive w
// in one row), computing all 64 co via 4 co-group MFMAs x 9 taps.
// D = A(weights, M=co) x B(activations, N=pixels):
//   B-frag: lane l reads qp[n][h+kh][w0+kw + (l&15)][ci=(l>>4)*16 ..+16] (dwordx4)
//   D-frag g: col = pixel = l&15, row = co-in-group = (l>>4)*4 + r
// Stores: 16 lanes -> 64B contiguous per (co,h) run in NCHW. Coalesced.
// ---------------------------------------------------------------------------
__global__ __launch_bounds__(256) void conv_kernel(const signed char* __restrict__ qp,
                                                   const signed char* __restrict__ wb,
                                                   const int* __restrict__ bias,
                                                   const float* __restrict__ deq,
                                                   float* __restrict__ out) {
    int wave = threadIdx.x >> 6;
    int lane = threadIdx.x & 63;
    int pbid = blockIdx.x * 4 + wave;        // 0..25087 (exact)
    int n = pbid / 784;                      // 784 = 112 rows * 7 blocks
    int r = pbid - n * 784;
    int h = r / 7;
    int pb = r - h * 7;
    int w0 = pb * 16;

    int laneoff = (lane & 15) * 64 + (lane >> 4) * 16;

    v4i acc0 = {0, 0, 0, 0}, acc1 = {0, 0, 0, 0}, acc2 = {0, 0, 0, 0}, acc3 = {0, 0, 0, 0};

    const signed char* wbl = wb + (size_t)lane * 16;
#pragma unroll
    for (int kh = 0; kh < 3; ++kh) {
        int hp = h + kh;                     // padded row index (input row h-1+kh)
        const signed char* arow = qp + ((size_t)(n * QP_HP + hp) * QP_WP + w0) * QP_C + laneoff;
        v4i wf[3][4];
#pragma unroll
        for (int kw = 0; kw < 3; ++kw)
#pragma unroll
            for (int g = 0; g < 4; ++g)
                wf[kw][g] = *reinterpret_cast<const v4i*>(wbl + (size_t)(((kh * 3 + kw) * 4 + g)) * 1024);
#pragma unroll
        for (int kw = 0; kw < 3; ++kw) {
            v4i bf = *reinterpret_cast<const v4i*>(arow + kw * 64);
            acc0 = __builtin_amdgcn_mfma_i32_16x16x64_i8(wf[kw][0], bf, acc0, 0, 0, 0);
            acc1 = __builtin_amdgcn_mfma_i32_16x16x64_i8(wf[kw][1], bf, acc1, 0, 0, 0);
            acc2 = __builtin_amdgcn_mfma_i32_16x16x64_i8(wf[kw][2], bf, acc2, 0, 0, 0);
            acc3 = __builtin_amdgcn_mfma_i32_16x16x64_i8(wf[kw][3], bf, acc3, 0, 0, 0);
        }
    }

    int p = lane & 15;
    int rq = lane >> 4;
    v4i accs[4] = {acc0, acc1, acc2, acc3};
#pragma unroll
    for (int g = 0; g < 4; ++g) {
#pragma unroll
        for (int rr = 0; rr < 4; ++rr) {
            int co = g * 16 + rq * 4 + rr;
            float val = (float)(accs[g][rr] + bias[co]) * deq[co];
            out[((size_t)((n * 64 + co) * 112) + h) * 112 + w0 + p] = val;
        }
    }
}

extern "C" void kernel_launch(void* const* d_in, const int* in_sizes, int n_in,
                              void* d_out, int out_size, void* d_ws, size_t ws_size,
                              hipStream_t stream) {
    const float* x   = (const float*)d_in[0];
    const int*   qw  = (const int*)d_in[1];    // int8 values widened to int32
    const int*   bias = (const int*)d_in[2];
    const float* deq = (const float*)d_in[3];
    float* out = (float*)d_out;

    signed char* qp = (signed char*)d_ws;
    signed char* wb = qp + QP_BYTES;

    // zero padded activation buffer (borders must be 0 each call)
    hipMemsetAsync(qp, 0, QP_BYTES, stream);

    quantize_kernel<<<32 * 112, 256, 0, stream>>>(x, qp);
    prepack_kernel<<<9, 256, 0, stream>>>(qw, wb);
    conv_kernel<<<25088 / 4, 256, 0, stream>>>(qp, wb, bias, deq, out);
}

// Round 2
// 70.212 us; speedup vs baseline: 1.3537x; 1.3537x over previous
//
#include <hip/hip_runtime.h>
#include <hip/hip_bf16.h>

typedef int v4i __attribute__((ext_vector_type(4)));

// Padded quantized activations: qp[n][hp][wp][c], hp,wp in [0,114), c in [0,64)
#define QP_N 32
#define QP_HP 114
#define QP_WP 114
#define QP_C 64
#define QP_BYTES ((size_t)QP_N * QP_HP * QP_WP * QP_C)   // 26,615,808

// ---------------------------------------------------------------------------
// Kernel 1: quantize + NCHW -> padded NHWC int8 transpose, with border zeroing
// (replaces the 26.6MB memset entirely).
// Grid: 32 * 114 blocks; block (n, hp). hp==0/113 -> zero row. Else transpose
// row h=hp-1 through LDS and also zero the wp=0 / wp=113 columns.
// ---------------------------------------------------------------------------
__global__ __launch_bounds__(256) void quantize_kernel(const float* __restrict__ x,
                                                       signed char* __restrict__ qp) {
    int nb = blockIdx.x;            // 0..3647
    int n = nb / QP_HP;
    int hp = nb - n * QP_HP;
    int t = threadIdx.x;
    signed char* rowbase = qp + ((size_t)n * QP_HP + hp) * QP_WP * QP_C;

    if (hp == 0 || hp == QP_HP - 1) {
        // zero the whole padded row: 114*64 = 7296 B = 228 * 32B
        if (t < 228) {
            int4 z = make_int4(0, 0, 0, 0);
            int4* dst = reinterpret_cast<int4*>(rowbase + t * 32);
            dst[0] = z;
            dst[1] = z;
        }
        return;
    }

    int h = hp - 1;
    __shared__ float lds[64][112];

    const float* xp = x + (size_t)n * 64 * 12544 + h * 112;  // x[n][c][h][w], c-plane stride 12544
#pragma unroll
    for (int j = 0; j < 7; ++j) {
        int fidx = j * 256 + t;      // 1792 float4 chunks total (64 rows * 28)
        int c = fidx / 28;
        int f = fidx - c * 28;
        float4 v = *reinterpret_cast<const float4*>(xp + (size_t)c * 12544 + f * 4);
        *reinterpret_cast<float4*>(&lds[c][f * 4]) = v;
    }
    __syncthreads();

    if (t < 224) {
        int w = t >> 1;              // 0..111
        int ch = (t & 1) * 32;       // channel half: 0 or 32
        int dw[8];
#pragma unroll
        for (int q = 0; q < 8; ++q) {
            int d = 0;
#pragma unroll
            for (int b = 0; b < 4; ++b) {
                float v = lds[ch + q * 4 + b][w];
                float s = rintf(v * 20.0f);                 // round-half-to-even, matches jnp.round
                s = fminf(127.0f, fmaxf(-128.0f, s));
                int iv = (int)s;
                d |= (iv & 0xff) << (8 * b);
            }
            dw[q] = d;
        }
        int4* dst = reinterpret_cast<int4*>(rowbase + (size_t)(w + 1) * QP_C + ch);
        dst[0] = make_int4(dw[0], dw[1], dw[2], dw[3]);
        dst[1] = make_int4(dw[4], dw[5], dw[6], dw[7]);
    } else if (t < 232) {
        // zero border columns wp=0 and wp=113 (64 B each = 4 int4 each)
        int i = t - 224;
        int col = (i >> 2) ? (QP_WP - 1) : 0;
        int part = i & 3;
        *reinterpret_cast<int4*>(rowbase + (size_t)col * QP_C + part * 16) = make_int4(0, 0, 0, 0);
    }
}

// ---------------------------------------------------------------------------
// Kernel 2: weight prepack into MFMA A-fragment layout.
// wb[frag][lane][16B], frag = (kh*3+kw)*4 + g.
// A-frag (M=co x K=ci): lane l holds A[m = l&15][k = (l>>4)*16 + j], j=0..15.
// co = g*16 + (l&15), ci = (l>>4)*16 + j.
// quant_weight arrives widened to int32: qw[((co*64+ci)*3+kh)*3+kw]
// ---------------------------------------------------------------------------
__global__ __launch_bounds__(256) void prepack_kernel(const int* __restrict__ qw,
                                                      signed char* __restrict__ wb) {
    int t = blockIdx.x * 256 + threadIdx.x;
    if (t >= 36 * 64) return;
    int lane = t & 63;
    int frag = t >> 6;               // 0..35
    int g = frag & 3;
    int tap = frag >> 2;             // kh*3+kw
    int kh = tap / 3;
    int kw = tap - kh * 3;
    int co = g * 16 + (lane & 15);
    int cibase = (lane >> 4) * 16;
    int dwv[4];
#pragma unroll
    for (int d = 0; d < 4; ++d) {
        int acc = 0;
#pragma unroll
        for (int b = 0; b < 4; ++b) {
            int ci = cibase + d * 4 + b;
            int v = qw[((co * 64 + ci) * 3 + kh) * 3 + kw];
            acc |= (v & 0xff) << (8 * b);
        }
        dwv[d] = acc;
    }
    *reinterpret_cast<int4*>(wb + (size_t)t * 16) = make_int4(dwv[0], dwv[1], dwv[2], dwv[3]);
}

// ---------------------------------------------------------------------------
// Kernel 3: implicit-GEMM conv. Weights staged in LDS (36 KB). Each wave
// computes 64 pixels x 64 co = 144 MFMAs, with 36 B-loads + 36 A ds_reads.
// A row (112 px) is covered by two overlapping wave-groups: w0=0 (px 0..63)
// and w0=48 (px 48..111); the overlap double-writes identical values.
//   B-frag: lane l reads qp[n][h+kh][w0+pb*16+kw + (l&15)][(l>>4)*16 ..+16]
//   D-frag g: col = pixel = l&15, row = co-in-group = (l>>4)*4 + rr
// ---------------------------------------------------------------------------
__global__ __launch_bounds__(256) void conv_kernel(const signed char* __restrict__ qp,
                                                   const signed char* __restrict__ wb,
                                                   const int* __restrict__ bias,
                                                   const float* __restrict__ deq,
                                                   float* __restrict__ out) {
    __shared__ signed char wlds[36864];
    int t = threadIdx.x;
#pragma unroll
    for (int i = 0; i < 9; ++i) {
        *reinterpret_cast<int4*>(&wlds[(size_t)(i * 256 + t) * 16]) =
            *reinterpret_cast<const int4*>(wb + (size_t)(i * 256 + t) * 16);
    }
    __syncthreads();

    int wave = t >> 6;
    int lane = t & 63;
    int wid = blockIdx.x * 4 + wave;         // 0..7167
    int n = wid / 224;                       // 224 = 112 rows * 2 groups
    int r = wid - n * 224;
    int h = r >> 1;
    int grp = r & 1;
    int w0 = grp * 48;                       // pixels w0 .. w0+63

    int laneoff = (lane & 15) * 64 + (lane >> 4) * 16;
    const signed char* wl = wlds + lane * 16;     // A-frag f at wl + f*1024

    v4i acc[4][4];                           // [pixel-block][co-group]
#pragma unroll
    for (int pb = 0; pb < 4; ++pb)
#pragma unroll
        for (int g = 0; g < 4; ++g)
            acc[pb][g] = (v4i){0, 0, 0, 0};

#pragma unroll
    for (int kh = 0; kh < 3; ++kh) {
        const signed char* arow =
            qp + ((size_t)(n * QP_HP + h + kh) * QP_WP + w0) * QP_C + laneoff;
#pragma unroll
        for (int kw = 0; kw < 3; ++kw) {
            v4i a0 = *reinterpret_cast<const v4i*>(wl + (size_t)(((kh * 3 + kw) * 4 + 0)) * 1024);
            v4i a1 = *reinterpret_cast<const v4i*>(wl + (size_t)(((kh * 3 + kw) * 4 + 1)) * 1024);
            v4i a2 = *reinterpret_cast<const v4i*>(wl + (size_t)(((kh * 3 + kw) * 4 + 2)) * 1024);
            v4i a3 = *reinterpret_cast<const v4i*>(wl + (size_t)(((kh * 3 + kw) * 4 + 3)) * 1024);
#pragma unroll
            for (int pb = 0; pb < 4; ++pb) {
                v4i bf = *reinterpret_cast<const v4i*>(arow + (size_t)(pb * 16 + kw) * QP_C);
                acc[pb][0] = __builtin_amdgcn_mfma_i32_16x16x64_i8(a0, bf, acc[pb][0], 0, 0, 0);
                acc[pb][1] = __builtin_amdgcn_mfma_i32_16x16x64_i8(a1, bf, acc[pb][1], 0, 0, 0);
                acc[pb][2] = __builtin_amdgcn_mfma_i32_16x16x64_i8(a2, bf, acc[pb][2], 0, 0, 0);
                acc[pb][3] = __builtin_amdgcn_mfma_i32_16x16x64_i8(a3, bf, acc[pb][3], 0, 0, 0);
            }
        }
    }

    int p = lane & 15;
    int rq = lane >> 4;
#pragma unroll
    for (int g = 0; g < 4; ++g) {
#pragma unroll
        for (int rr = 0; rr < 4; ++rr) {
            int co = g * 16 + rq * 4 + rr;
            int bv = bias[co];
            float dv = deq[co];
            float* orow = out + ((size_t)((n * 64 + co) * 112) + h) * 112 + w0 + p;
#pragma unroll
            for (int pb = 0; pb < 4; ++pb) {
                orow[pb * 16] = (float)(acc[pb][g][rr] + bv) * dv;
            }
        }
    }
}

extern "C" void kernel_launch(void* const* d_in, const int* in_sizes, int n_in,
                              void* d_out, int out_size, void* d_ws, size_t ws_size,
                              hipStream_t stream) {
    const float* x   = (const float*)d_in[0];
    const int*   qw  = (const int*)d_in[1];    // int8 values widened to int32
    const int*   bias = (const int*)d_in[2];
    const float* deq = (const float*)d_in[3];
    float* out = (float*)d_out;

    signed char* qp = (signed char*)d_ws;
    signed char* wb = qp + QP_BYTES;

    quantize_kernel<<<QP_N * QP_HP, 256, 0, stream>>>(x, qp);
    prepack_kernel<<<9, 256, 0, stream>>>(qw, wb);
    conv_kernel<<<7168 / 4, 256, 0, stream>>>(qp, wb, bias, deq, out);
}

// Round 3
// 62.649 us; speedup vs baseline: 1.5171x; 1.1207x over previous
//
#include <hip/hip_runtime.h>
#include <hip/hip_bf16.h>

typedef int v4i __attribute__((ext_vector_type(4)));

// Padded quantized activations: qp[n][hp][wp][c], hp,wp in [0,114), c in [0,64)
#define QP_N 32
#define QP_HP 114
#define QP_WP 114
#define QP_C 64
#define QP_BYTES ((size_t)QP_N * QP_HP * QP_WP * QP_C)   // 26,615,808

#define QBLOCKS (QP_N * QP_HP)      // 3648 quantize blocks
#define PBLOCKS 9                   // prepack blocks folded into same launch

// ---------------------------------------------------------------------------
// Kernel 1: quantize + NCHW -> padded NHWC int8 transpose, with border zeroing.
// Blocks [0, 3648): block (n, hp). hp==0/113 -> zero row. Else transpose row
// h=hp-1 through LDS and zero the wp=0 / wp=113 columns.
// Blocks [3648, 3657): weight prepack into MFMA B-fragment layout.
//   wb[frag][lane][16B], frag = (kh*3+kw)*4 + g.
//   B-frag (K=ci x N=co): lane l holds B[k=(l>>4)*16+j][n = l&15], j=0..15.
//   co = g*16 + (l&15), ci = (l>>4)*16 + j.  qw arrives widened to int32.
// ---------------------------------------------------------------------------
__global__ __launch_bounds__(256) void quantize_kernel(const float* __restrict__ x,
                                                       signed char* __restrict__ qp,
                                                       const int* __restrict__ qw,
                                                       signed char* __restrict__ wb) {
    int t = threadIdx.x;

    if (blockIdx.x >= QBLOCKS) {
        // ---- prepack path ----
        int idx = (blockIdx.x - QBLOCKS) * 256 + t;
        if (idx >= 36 * 64) return;
        int lane = idx & 63;
        int frag = idx >> 6;             // 0..35
        int g = frag & 3;
        int tap = frag >> 2;             // kh*3+kw
        int kh = tap / 3;
        int kw = tap - kh * 3;
        int co = g * 16 + (lane & 15);
        int cibase = (lane >> 4) * 16;
        int dwv[4];
#pragma unroll
        for (int d = 0; d < 4; ++d) {
            int acc = 0;
#pragma unroll
            for (int b = 0; b < 4; ++b) {
                int ci = cibase + d * 4 + b;
                int v = qw[((co * 64 + ci) * 3 + kh) * 3 + kw];
                acc |= (v & 0xff) << (8 * b);
            }
            dwv[d] = acc;
        }
        *reinterpret_cast<int4*>(wb + (size_t)idx * 16) = make_int4(dwv[0], dwv[1], dwv[2], dwv[3]);
        return;
    }

    int nb = blockIdx.x;            // 0..3647
    int n = nb / QP_HP;
    int hp = nb - n * QP_HP;
    signed char* rowbase = qp + ((size_t)n * QP_HP + hp) * QP_WP * QP_C;

    if (hp == 0 || hp == QP_HP - 1) {
        // zero the whole padded row: 114*64 = 7296 B = 228 * 32B
        if (t < 228) {
            int4 z = make_int4(0, 0, 0, 0);
            int4* dst = reinterpret_cast<int4*>(rowbase + t * 32);
            dst[0] = z;
            dst[1] = z;
        }
        return;
    }

    int h = hp - 1;
    __shared__ float lds[64][112];

    const float* xp = x + (size_t)n * 64 * 12544 + h * 112;  // x[n][c][h][w], c-plane stride 12544
#pragma unroll
    for (int j = 0; j < 7; ++j) {
        int fidx = j * 256 + t;      // 1792 float4 chunks total (64 rows * 28)
        int c = fidx / 28;
        int f = fidx - c * 28;
        float4 v = *reinterpret_cast<const float4*>(xp + (size_t)c * 12544 + f * 4);
        *reinterpret_cast<float4*>(&lds[c][f * 4]) = v;
    }
    __syncthreads();

    if (t < 224) {
        int w = t >> 1;              // 0..111
        int ch = (t & 1) * 32;       // channel half: 0 or 32
        int dw[8];
#pragma unroll
        for (int q = 0; q < 8; ++q) {
            int d = 0;
#pragma unroll
            for (int b = 0; b < 4; ++b) {
                float v = lds[ch + q * 4 + b][w];
                float s = rintf(v * 20.0f);                 // round-half-to-even, matches jnp.round
                s = fminf(127.0f, fmaxf(-128.0f, s));
                int iv = (int)s;
                d |= (iv & 0xff) << (8 * b);
            }
            dw[q] = d;
        }
        int4* dst = reinterpret_cast<int4*>(rowbase + (size_t)(w + 1) * QP_C + ch);
        dst[0] = make_int4(dw[0], dw[1], dw[2], dw[3]);
        dst[1] = make_int4(dw[4], dw[5], dw[6], dw[7]);
    } else if (t < 232) {
        // zero border columns wp=0 and wp=113 (64 B each = 4 int4 each)
        int i = t - 224;
        int col = (i >> 2) ? (QP_WP - 1) : 0;
        int part = i & 3;
        *reinterpret_cast<int4*>(rowbase + (size_t)col * QP_C + part * 16) = make_int4(0, 0, 0, 0);
    }
}

// ---------------------------------------------------------------------------
// Kernel 2: implicit-GEMM conv, A = activations (M=16 px), B = weights (N=16 co).
// Weights staged in LDS (36 KB). Row 112 px split as 64 + 48 (no overlap):
// even waves: 4 px-blocks at w0=0; odd waves: 3 px-blocks at w0=64.
//   A-frag: lane l reads qp[n][h+kh][w0+pb*16+kw + (l&15)][(l>>4)*16 ..+16]
//   D-frag (pb,g): co = g*16 + (l&15), pixels (l>>4)*4 .. +3  -> float4 stores
// ---------------------------------------------------------------------------
template <int NPB>
__device__ __forceinline__ void conv_tile(const signed char* __restrict__ abase,
                                          const signed char* wl,
                                          const int* __restrict__ bias,
                                          const float* __restrict__ deq,
                                          float* __restrict__ outp,
                                          int lane) {
    v4i acc[NPB][4];
#pragma unroll
    for (int pb = 0; pb < NPB; ++pb)
#pragma unroll
        for (int g = 0; g < 4; ++g)
            acc[pb][g] = (v4i){0, 0, 0, 0};

#pragma unroll
    for (int kh = 0; kh < 3; ++kh) {
        const signed char* arow = abase + (size_t)kh * (QP_WP * QP_C);
#pragma unroll
        for (int kw = 0; kw < 3; ++kw) {
            v4i w0f = *reinterpret_cast<const v4i*>(wl + (size_t)(((kh * 3 + kw) * 4 + 0)) * 1024);
            v4i w1f = *reinterpret_cast<const v4i*>(wl + (size_t)(((kh * 3 + kw) * 4 + 1)) * 1024);
            v4i w2f = *reinterpret_cast<const v4i*>(wl + (size_t)(((kh * 3 + kw) * 4 + 2)) * 1024);
            v4i w3f = *reinterpret_cast<const v4i*>(wl + (size_t)(((kh * 3 + kw) * 4 + 3)) * 1024);
#pragma unroll
            for (int pb = 0; pb < NPB; ++pb) {
                v4i af = *reinterpret_cast<const v4i*>(arow + (size_t)(pb * 16 + kw) * QP_C);
                acc[pb][0] = __builtin_amdgcn_mfma_i32_16x16x64_i8(af, w0f, acc[pb][0], 0, 0, 0);
                acc[pb][1] = __builtin_amdgcn_mfma_i32_16x16x64_i8(af, w1f, acc[pb][1], 0, 0, 0);
                acc[pb][2] = __builtin_amdgcn_mfma_i32_16x16x64_i8(af, w2f, acc[pb][2], 0, 0, 0);
                acc[pb][3] = __builtin_amdgcn_mfma_i32_16x16x64_i8(af, w3f, acc[pb][3], 0, 0, 0);
            }
        }
    }

    int cbase = lane & 15;           // co within group
    int pq = (lane >> 4) * 4;        // pixel quad start within 16-px block
#pragma unroll
    for (int g = 0; g < 4; ++g) {
        int co = g * 16 + cbase;
        int bv = bias[co];
        float dv = deq[co];
        float* orow = outp + (size_t)co * 12544 + pq;
#pragma unroll
        for (int pb = 0; pb < NPB; ++pb) {
            float4 v;
            v.x = (float)(acc[pb][g][0] + bv) * dv;
            v.y = (float)(acc[pb][g][1] + bv) * dv;
            v.z = (float)(acc[pb][g][2] + bv) * dv;
            v.w = (float)(acc[pb][g][3] + bv) * dv;
            *reinterpret_cast<float4*>(orow + pb * 16) = v;
        }
    }
}

__global__ __launch_bounds__(256) void conv_kernel(const signed char* __restrict__ qp,
                                                   const signed char* __restrict__ wb,
                                                   const int* __restrict__ bias,
                                                   const float* __restrict__ deq,
                                                   float* __restrict__ out) {
    __shared__ signed char wlds[36864];
    int t = threadIdx.x;
#pragma unroll
    for (int i = 0; i < 9; ++i) {
        *reinterpret_cast<int4*>(&wlds[(size_t)(i * 256 + t) * 16]) =
            *reinterpret_cast<const int4*>(wb + (size_t)(i * 256 + t) * 16);
    }
    __syncthreads();

    int wave = t >> 6;
    int lane = t & 63;
    int wid = blockIdx.x * 4 + wave;         // 0..7167
    int n = wid / 224;                       // 224 = 112 rows * 2 halves
    int r = wid - n * 224;
    int h = r >> 1;
    int half = r & 1;
    int w0 = half ? 64 : 0;

    int laneoff = (lane & 15) * 64 + (lane >> 4) * 16;
    const signed char* abase =
        qp + ((size_t)(n * QP_HP + h) * QP_WP + w0) * QP_C + laneoff;
    const signed char* wl = wlds + lane * 16;     // B-frag f at wl + f*1024
    float* outp = out + (size_t)n * 64 * 12544 + h * 112 + w0;

    if (half == 0)
        conv_tile<4>(abase, wl, bias, deq, outp, lane);
    else
        conv_tile<3>(abase, wl, bias, deq, outp, lane);
}

extern "C" void kernel_launch(void* const* d_in, const int* in_sizes, int n_in,
                              void* d_out, int out_size, void* d_ws, size_t ws_size,
                              hipStream_t stream) {
    const float* x   = (const float*)d_in[0];
    const int*   qw  = (const int*)d_in[1];    // int8 values widened to int32
    const int*   bias = (const int*)d_in[2];
    const float* deq = (const float*)d_in[3];
    float* out = (float*)d_out;

    signed char* qp = (signed char*)d_ws;
    signed char* wb = qp + QP_BYTES;

    quantize_kernel<<<QBLOCKS + PBLOCKS, 256, 0, stream>>>(x, qp, qw, wb);
    conv_kernel<<<7168 / 4, 256, 0, stream>>>(qp, wb, bias, deq, out);
}